// Round 7
// baseline (16722.972 us; speedup 1.0000x reference)
//
#include <hip/hip_runtime.h>
#include <math.h>

// Dims (fixed by the problem)
#define HH   50          // hidden
#define GG   150         // 3H
#define XGS  152         // xg row stride (padded)
#define TTT  2048        // T
#define NB   64          // batch B
#define MTOT (TTT*NB)    // 131072 rows per layer
#define D0   128         // layer-0 input dim

static __device__ __forceinline__ float sigm(float x) {
    return 1.f / (1.f + __expf(-x));
}
static __device__ __forceinline__ float tanh_f(float x) {
    return 1.f - 2.f / (__expf(2.f * x) + 1.f);   // saturates correctly at +/-inf
}

static __device__ __forceinline__ void fma4(float4& a, float s, const float4& w) {
    a.x += s * w.x; a.y += s * w.y; a.z += s * w.z; a.w += s * w.w;
}

static __device__ __forceinline__ float bcast(float v, int k) {
    // wave-uniform broadcast of lane k's value (compile-time k after unroll)
    return __uint_as_float(__builtin_amdgcn_readlane(__float_as_uint(v), k));
}

// ---------------- Layer-0 input projection: Xg = X0 @ W + bi ----------------
// (unchanged from round 5 -- proven)
__global__ __launch_bounds__(256) void proj0_kernel(
    const float* __restrict__ x,              // [64,2048,128] f32
    const float* __restrict__ W,              // [128,150] f32
    const float* __restrict__ bias,           // [2,150] f32 (bi = bias[0])
    float* __restrict__ xg)                   // [MTOT,XGS] f32
{
    __shared__ float xs[128][36];             // k-quarter of x, stride 36 (18.4 KB)
    __shared__ float Wp[32][32];              // k-quarter of W cols for this tile (4 KB)
    const int tid  = threadIdx.x;
    const int m0   = blockIdx.x * 128;
    const int c0   = blockIdx.y * 32;         // col-tile base: 0,32,64,96,128
    const int rowq = tid >> 3;                // 0..31
    const int colq = tid & 7;                 // 0..7

    float4 acc[4];
    #pragma unroll
    for (int j = 0; j < 4; ++j) acc[j] = make_float4(0.f, 0.f, 0.f, 0.f);

    for (int q = 0; q < 4; ++q) {             // K quarters of 32
        if (q) __syncthreads();
        for (int i = tid; i < 128 * 8; i += 256) {
            int r = i >> 3, k4 = (i & 7) * 4;
            int row = m0 + r, t = row >> 6, b = row & 63;
            *(float4*)&xs[r][k4] =
                *(const float4*)&x[((size_t)b * TTT + t) * D0 + q * 32 + k4];
        }
        for (int i = tid; i < 32 * 32; i += 256) {
            int k = i >> 5, c = i & 31, gc = c0 + c;
            Wp[k][c] = (gc < GG) ? W[(q * 32 + k) * GG + gc] : 0.f;
        }
        __syncthreads();
        const float* xr0 = xs[rowq * 4 + 0];
        const float* xr1 = xs[rowq * 4 + 1];
        const float* xr2 = xs[rowq * 4 + 2];
        const float* xr3 = xs[rowq * 4 + 3];
        for (int k = 0; k < 32; k += 4) {
            float4 w0 = *(const float4*)&Wp[k + 0][colq * 4];
            float4 w1 = *(const float4*)&Wp[k + 1][colq * 4];
            float4 w2 = *(const float4*)&Wp[k + 2][colq * 4];
            float4 w3 = *(const float4*)&Wp[k + 3][colq * 4];
            float4 x0 = *(const float4*)&xr0[k];
            float4 x1 = *(const float4*)&xr1[k];
            float4 x2 = *(const float4*)&xr2[k];
            float4 x3 = *(const float4*)&xr3[k];
            fma4(acc[0], x0.x, w0); fma4(acc[0], x0.y, w1);
            fma4(acc[0], x0.z, w2); fma4(acc[0], x0.w, w3);
            fma4(acc[1], x1.x, w0); fma4(acc[1], x1.y, w1);
            fma4(acc[1], x1.z, w2); fma4(acc[1], x1.w, w3);
            fma4(acc[2], x2.x, w0); fma4(acc[2], x2.y, w1);
            fma4(acc[2], x2.z, w2); fma4(acc[2], x2.w, w3);
            fma4(acc[3], x3.x, w0); fma4(acc[3], x3.y, w1);
            fma4(acc[3], x3.z, w2); fma4(acc[3], x3.w, w3);
        }
    }
    const int cc = c0 + colq * 4;
    if (cc <= XGS - 4) {                      // cc <= 148; cols 150/151 unread pad
        float4 bv = *(const float4*)&bias[cc];
        #pragma unroll
        for (int j = 0; j < 4; ++j) {
            float4 o;
            o.x = acc[j].x + bv.x; o.y = acc[j].y + bv.y;
            o.z = acc[j].z + bv.z; o.w = acc[j].w + bv.w;
            *(float4*)&xg[(size_t)(m0 + rowq * 4 + j) * XGS + cc] = o;
        }
    }
}

// ---------------- Layer-0 GRU: h in registers, readlane broadcast ----------------
// (unchanged from round 5 -- proven; consumes xg with XGS stride)
template<int WPB, int RPW>
__global__ __launch_bounds__(WPB * 64) void gru_reg(
    const float* __restrict__ xg,             // [dn*Nbatch, XGS] f32 (includes bi)
    const float* __restrict__ U,              // [50,150] f32
    const float* __restrict__ bias,           // [2,150] f32 (br = bias+150)
    float* __restrict__ Xout,                 // [MTOT,50] f32 time-major
    int dn, int Nbatch, int ngroups)
{
    constexpr int R = WPB * RPW;              // rows per block per group
    __shared__ __align__(16) float Ut[HH][HH][4];   // [k][unit][{z,r,h,0}] 40 KB

    const int tid  = threadIdx.x;
    const int wav  = tid >> 6;
    const int lane = tid & 63;

    for (int i = tid; i < HH * HH; i += WPB * 64)
        Ut[i / HH][i - (i / HH) * HH][3] = 0.f;
    for (int i = tid; i < HH * GG; i += WPB * 64) {
        int k = i / GG, cc = i - k * GG;
        Ut[k][cc % HH][cc / HH] = U[i];       // U cols: [z|r|h] blocks of 50
    }
    __syncthreads();                          // the only block-wide barrier

    const int c  = lane;
    const int cb = (c < HH) ? c : HH - 1;     // clamped for loads (lanes 50..63)

    const float bz  = bias[GG + cb];
    const float brr = bias[GG + HH + cb];
    const float bh  = bias[GG + 2 * HH + cb];

    for (int grp = blockIdx.x; grp < ngroups; grp += gridDim.x) {
        const int row0 = grp * R + wav * RPW;
        float h[RPW];
        #pragma unroll
        for (int j = 0; j < RPW; ++j) h[j] = 0.f;
        size_t obase[RPW];
        #pragma unroll
        for (int j = 0; j < RPW; ++j) {
            int nr = row0 + j;
            obase[j] = ((size_t)((nr >> 6) * dn) * NB + (nr & 63)) * HH + cb;
        }
        const float* gb = xg + (size_t)row0 * XGS;

        float px[RPW], pr[RPW], ph[RPW];
        #pragma unroll
        for (int j = 0; j < RPW; ++j) {       // preload step 0
            const float* g = gb + (size_t)j * XGS;
            px[j] = g[cb]; pr[j] = g[HH + cb]; ph[j] = g[2 * HH + cb];
        }

        for (int s = 0; s < dn; ++s) {
            const int sn = (s + 1 < dn) ? s + 1 : s;
            float nx[RPW], nrr[RPW], nh[RPW];
            #pragma unroll
            for (int j = 0; j < RPW; ++j) {
                const float* g = gb + ((size_t)sn * Nbatch + j) * XGS;
                nx[j] = g[cb]; nrr[j] = g[HH + cb]; nh[j] = g[2 * HH + cb];
            }
            float az[RPW], ar[RPW], ah[RPW];
            #pragma unroll
            for (int j = 0; j < RPW; ++j) { az[j] = bz; ar[j] = brr; ah[j] = bh; }
            #pragma unroll
            for (int k = 0; k < HH; ++k) {
                float4 w = *(const float4*)&Ut[k][c < HH ? c : 0][0];
                #pragma unroll
                for (int j = 0; j < RPW; ++j) {
                    float hk = bcast(h[j], k);
                    az[j] += hk * w.x;
                    ar[j] += hk * w.y;
                    ah[j] += hk * w.z;
                }
            }
            #pragma unroll
            for (int j = 0; j < RPW; ++j) {
                float z  = sigm(px[j] + az[j]);
                float r  = sigm(pr[j] + ar[j]);
                float hh = tanh_f(ph[j] + r * ah[j]);
                float hn = z * h[j] + (1.f - z) * hh;
                h[j] = hn;
                if (c < HH) Xout[obase[j] + (size_t)s * NB * HH] = hn;
            }
            #pragma unroll
            for (int j = 0; j < RPW; ++j) { px[j] = nx[j]; pr[j] = nrr[j]; ph[j] = nh[j]; }
        }
    }
}

// ---------------- Fused projection + GRU (layers 1..5), spill-safe ----------------
// Two SEQUENTIAL k-loops per step, each structurally identical to gru_reg's
// proven loop (1 ds_read_b128 + RPW readlane + 3*RPW FMA per k): loop 1 does
// the x-projection against Wt, loop 2 the recurrence against Ut. Round 6's
// single merged loop doubled per-k register footprint inside a 1700-instr
// unrolled body -> accumulator spill (7.26 GB scratch traffic, VALUBusy 2.4%).
// WPB=4 (256 thr), LDS = Ut+Wt = 80 KB -> 2 blocks/CU (8 waves/CU).
template<int WPB, int RPW>
__global__ __launch_bounds__(WPB * 64) void gru_fused(
    const float* __restrict__ Xin,            // [dn*Nbatch, HH] f32 (prev layer)
    const float* __restrict__ W,              // [50,150] f32
    const float* __restrict__ U,              // [50,150] f32
    const float* __restrict__ bias,           // [2,150] f32
    float* __restrict__ Xout,                 // [MTOT,50] f32 time-major
    int dn, int Nbatch, int ngroups)
{
    constexpr int R = WPB * RPW;              // rows per block per group
    __shared__ __align__(16) float Ut[HH][HH][4];   // 40 KB
    __shared__ __align__(16) float Wt[HH][HH][4];   // 40 KB

    const int tid  = threadIdx.x;
    const int wav  = tid >> 6;
    const int lane = tid & 63;

    for (int i = tid; i < HH * HH; i += WPB * 64) {
        Ut[i / HH][i - (i / HH) * HH][3] = 0.f;
        Wt[i / HH][i - (i / HH) * HH][3] = 0.f;
    }
    for (int i = tid; i < HH * GG; i += WPB * 64) {
        int k = i / GG, cc = i - k * GG;
        Ut[k][cc % HH][cc / HH] = U[i];
        Wt[k][cc % HH][cc / HH] = W[i];
    }
    __syncthreads();                          // the only block-wide barrier

    const int c  = lane;
    const int cb = (c < HH) ? c : HH - 1;

    const float biz = bias[cb];
    const float bir = bias[HH + cb];
    const float bih = bias[2 * HH + cb];
    const float brz = bias[GG + cb];
    const float brr = bias[GG + HH + cb];
    const float brh = bias[GG + 2 * HH + cb];

    for (int grp = blockIdx.x; grp < ngroups; grp += gridDim.x) {
        const int row0 = grp * R + wav * RPW;
        float h[RPW];
        #pragma unroll
        for (int j = 0; j < RPW; ++j) h[j] = 0.f;
        size_t obase[RPW];
        #pragma unroll
        for (int j = 0; j < RPW; ++j) {
            int nr = row0 + j;
            obase[j] = ((size_t)((nr >> 6) * dn) * NB + (nr & 63)) * HH + cb;
        }
        const float* gb = Xin + (size_t)row0 * HH;

        float px[RPW];
        #pragma unroll
        for (int j = 0; j < RPW; ++j) px[j] = gb[(size_t)j * HH + cb];   // step 0

        for (int s = 0; s < dn; ++s) {
            const int sn = (s + 1 < dn) ? s + 1 : s;
            float nx[RPW];
            #pragma unroll
            for (int j = 0; j < RPW; ++j)
                nx[j] = gb[((size_t)sn * Nbatch + j) * HH + cb];

            // ---- loop 1: x-projection  gz/gr/gh = x @ W  (gru_reg shape) ----
            float gz[RPW], gr[RPW], gh[RPW];
            #pragma unroll
            for (int j = 0; j < RPW; ++j) { gz[j] = biz; gr[j] = bir; gh[j] = bih; }
            #pragma unroll
            for (int k = 0; k < HH; ++k) {
                float4 w = *(const float4*)&Wt[k][c < HH ? c : 0][0];
                #pragma unroll
                for (int j = 0; j < RPW; ++j) {
                    float xk = bcast(px[j], k);
                    gz[j] += xk * w.x;
                    gr[j] += xk * w.y;
                    gh[j] += xk * w.z;
                }
            }
            // ---- loop 2: recurrence  az/ar/ah = h @ U + br  (gru_reg shape) ----
            float az[RPW], ar[RPW], ah[RPW];
            #pragma unroll
            for (int j = 0; j < RPW; ++j) { az[j] = brz; ar[j] = brr; ah[j] = brh; }
            #pragma unroll
            for (int k = 0; k < HH; ++k) {
                float4 w = *(const float4*)&Ut[k][c < HH ? c : 0][0];
                #pragma unroll
                for (int j = 0; j < RPW; ++j) {
                    float hk = bcast(h[j], k);
                    az[j] += hk * w.x;
                    ar[j] += hk * w.y;
                    ah[j] += hk * w.z;
                }
            }
            // ---- gates + state update ----
            #pragma unroll
            for (int j = 0; j < RPW; ++j) {
                float z  = sigm(gz[j] + az[j]);
                float r  = sigm(gr[j] + ar[j]);
                float hh = tanh_f(gh[j] + r * ah[j]);
                float hn = z * h[j] + (1.f - z) * hh;
                h[j] = hn;
                if (c < HH) Xout[obase[j] + (size_t)s * NB * HH] = hn;
            }
            #pragma unroll
            for (int j = 0; j < RPW; ++j) px[j] = nx[j];
        }
    }
}

// ---------------- Head: split-K partial GEMM (no bias/relu here) ----------------
__global__ __launch_bounds__(256) void dense2_kernel(
    const float* __restrict__ X,              // [MTOT,50] f32 final layer (time-major)
    const float* __restrict__ W2,             // [1600,1600] f32
    float* __restrict__ part)                 // [16,64,1600] f32 partials
{
    __shared__ float fs[8][100];              // 3.2 KB
    const int tid = threadIdx.x;
    const int c  = blockIdx.x * 256 + tid;
    const int r0 = blockIdx.y * 8;
    const int kz = blockIdx.z;
    for (int i = tid; i < 8 * 100; i += 256) {
        int r = i / 100, fl = i - r * 100;
        int f = kz * 100 + fl, j = f / HH, k = f - j * HH;
        fs[r][fl] = X[((size_t)(TTT - 32 + j) * NB + (r0 + r)) * HH + k];
    }
    __syncthreads();
    if (c < 1600) {
        float a[8] = {0, 0, 0, 0, 0, 0, 0, 0};
        const float* w = W2 + (size_t)kz * 100 * 1600 + c;
        for (int fl = 0; fl < 100; ++fl) {
            float wv = w[(size_t)fl * 1600];
            #pragma unroll
            for (int r = 0; r < 8; ++r) a[r] += fs[r][fl] * wv;
        }
        #pragma unroll
        for (int r = 0; r < 8; ++r)
            part[((size_t)kz * NB + r0 + r) * 1600 + c] = a[r];
    }
}

// ---------------- Classifier: sum partials + bias + relu, then softmax ----------------
__global__ __launch_bounds__(256) void cls_kernel(
    const float* __restrict__ part,           // [16,64,1600] f32 partials
    const float* __restrict__ b2,             // [1600] f32
    const float* __restrict__ Wc,             // [1600,41] f32
    const float* __restrict__ bc,             // [41] f32
    float* __restrict__ out)                  // [64,41] f32
{
    __shared__ float hrow[1600];
    __shared__ float lg[41];
    __shared__ float red[2];
    const int b = blockIdx.x;
    const int t = threadIdx.x;
    for (int i = t; i < 1600; i += 256) {
        float s = b2[i];
        #pragma unroll 4
        for (int kz = 0; kz < 16; ++kz)
            s += part[((size_t)kz * NB + b) * 1600 + i];
        hrow[i] = s > 0.f ? s : 0.f;
    }
    __syncthreads();
    if (t < 41) {
        float acc = bc[t];
        for (int f = 0; f < 1600; ++f) acc += hrow[f] * Wc[f * 41 + t];
        lg[t] = acc;
    }
    __syncthreads();
    if (t == 0) {
        float mx = lg[0];
        for (int i = 1; i < 41; ++i) mx = fmaxf(mx, lg[i]);
        red[0] = mx;
    }
    __syncthreads();
    if (t < 41) lg[t] = expf(lg[t] - red[0]);
    __syncthreads();
    if (t == 0) {
        float sm = 0.f;
        for (int i = 0; i < 41; ++i) sm += lg[i];
        red[1] = 1.f / sm;
    }
    __syncthreads();
    if (t < 41) out[b * 41 + t] = lg[t] * red[1];
}

extern "C" void kernel_launch(void* const* d_in, const int* in_sizes, int n_in,
                              void* d_out, int out_size, void* d_ws, size_t ws_size,
                              hipStream_t stream)
{
    const float* x   = (const float*)d_in[0];    // [64,2048,128]
    const float* W0  = (const float*)d_in[1];    // [128,150]
    const float* U0  = (const float*)d_in[2];    // [50,150]
    const float* b0  = (const float*)d_in[3];    // [2,150]
    const float* Ws  = (const float*)d_in[4];    // [5,50,150]
    const float* Us  = (const float*)d_in[5];    // [5,50,150]
    const float* bs  = (const float*)d_in[6];    // [5,2,150]
    const float* W2  = (const float*)d_in[7];    // [1600,1600]
    const float* b2  = (const float*)d_in[8];    // [1600]
    const float* Wc  = (const float*)d_in[9];    // [1600,41]
    const float* bc  = (const float*)d_in[10];   // [41]

    // Workspace layout:
    //   region1 = MTOT*XGS floats (79.7 MB): xg (layer 0) -> bufB (layers 1..5)
    //             part lives at region1 + MTOT*HH (disjoint from bufB)
    //   bufA    = MTOT*HH floats (26.2 MB)
    float* region1 = (float*)d_ws;
    float* xg   = region1;
    float* bufB = region1;                             // reuses xg after layer 0
    float* part = region1 + (size_t)MTOT * HH;         // disjoint from bufB
    float* bufA = region1 + (size_t)MTOT * XGS;

    static const int rates[6] = {32, 64, 128, 256, 512, 1024};

    // ---- layer 0: GEMM proj + gru_reg (round-5 proven config) ----
    proj0_kernel<<<dim3(MTOT / 128, 5), 256, 0, stream>>>(x, W0, b0, xg);
    {
        int dn = TTT / rates[0], Nbatch = rates[0] * NB;   // 64, 2048
        int ngroups = Nbatch / 4;                          // R=4 for <4,1>
        int grid = ngroups < 1024 ? ngroups : 1024;
        gru_reg<4, 1><<<grid, 256, 0, stream>>>(xg, U0, b0, bufA, dn, Nbatch, ngroups);
    }

    // ---- layers 1..5: fused proj+gru <4,4>, ping-pong bufA <-> bufB ----
    const float* cur = bufA;
    for (int l = 1; l < 6; ++l) {
        const float* Wl = Ws + (size_t)(l - 1) * HH * GG;
        const float* Ul = Us + (size_t)(l - 1) * HH * GG;
        const float* bl = bs + (size_t)(l - 1) * 2 * GG;
        int rate = rates[l];
        int Nbatch = rate * NB;
        int dn = TTT / rate;
        float* dst = (cur == bufA) ? bufB : bufA;
        int ngroups = Nbatch / 16;                         // R=16 for <4,4>
        int grid = ngroups < 512 ? ngroups : 512;
        gru_fused<4, 4><<<grid, 256, 0, stream>>>(cur, Wl, Ul, bl, dst, dn, Nbatch, ngroups);
        cur = dst;
    }

    // head: split-K dense2 into partials, reduce+relu inside cls
    dense2_kernel<<<dim3(7, 8, 16), 256, 0, stream>>>(cur, W2, part);
    cls_kernel<<<NB, 256, 0, stream>>>(part, b2, Wc, bc, (float*)d_out);
}

// Round 8
// 1130.276 us; speedup vs baseline: 14.7955x; 14.7955x over previous
//
#include <hip/hip_runtime.h>
#include <math.h>

// Dims (fixed by the problem)
#define HH   50          // hidden
#define GG   150         // 3H
#define XGS  152         // xg row stride (padded)
#define TTT  2048        // T
#define NB   64          // batch B
#define MTOT (TTT*NB)    // 131072 rows per layer
#define D0   128         // layer-0 input dim

static __device__ __forceinline__ float sigm(float x) {
    return 1.f / (1.f + __expf(-x));
}
static __device__ __forceinline__ float tanh_f(float x) {
    return 1.f - 2.f / (__expf(2.f * x) + 1.f);   // saturates correctly at +/-inf
}

static __device__ __forceinline__ void fma4(float4& a, float s, const float4& w) {
    a.x += s * w.x; a.y += s * w.y; a.z += s * w.z; a.w += s * w.w;
}

static __device__ __forceinline__ float bcast(float v, int k) {
    // wave-uniform broadcast of lane k's value; k may be a uniform runtime
    // value (v_readlane_b32 with SGPR lane index)
    return __uint_as_float(__builtin_amdgcn_readlane(__float_as_uint(v), k));
}

// ---------------- Layer-0 input projection: Xg = X0 @ W + bi ----------------
// (unchanged -- proven, ~110 us)
__global__ __launch_bounds__(256) void proj0_kernel(
    const float* __restrict__ x,              // [64,2048,128] f32
    const float* __restrict__ W,              // [128,150] f32
    const float* __restrict__ bias,           // [2,150] f32 (bi = bias[0])
    float* __restrict__ xg)                   // [MTOT,XGS] f32
{
    __shared__ float xs[128][36];             // k-quarter of x, stride 36 (18.4 KB)
    __shared__ float Wp[32][32];              // k-quarter of W cols for this tile (4 KB)
    const int tid  = threadIdx.x;
    const int m0   = blockIdx.x * 128;
    const int c0   = blockIdx.y * 32;         // col-tile base: 0,32,64,96,128
    const int rowq = tid >> 3;                // 0..31
    const int colq = tid & 7;                 // 0..7

    float4 acc[4];
    #pragma unroll
    for (int j = 0; j < 4; ++j) acc[j] = make_float4(0.f, 0.f, 0.f, 0.f);

    for (int q = 0; q < 4; ++q) {             // K quarters of 32
        if (q) __syncthreads();
        for (int i = tid; i < 128 * 8; i += 256) {
            int r = i >> 3, k4 = (i & 7) * 4;
            int row = m0 + r, t = row >> 6, b = row & 63;
            *(float4*)&xs[r][k4] =
                *(const float4*)&x[((size_t)b * TTT + t) * D0 + q * 32 + k4];
        }
        for (int i = tid; i < 32 * 32; i += 256) {
            int k = i >> 5, c = i & 31, gc = c0 + c;
            Wp[k][c] = (gc < GG) ? W[(q * 32 + k) * GG + gc] : 0.f;
        }
        __syncthreads();
        const float* xr0 = xs[rowq * 4 + 0];
        const float* xr1 = xs[rowq * 4 + 1];
        const float* xr2 = xs[rowq * 4 + 2];
        const float* xr3 = xs[rowq * 4 + 3];
        for (int k = 0; k < 32; k += 4) {
            float4 w0 = *(const float4*)&Wp[k + 0][colq * 4];
            float4 w1 = *(const float4*)&Wp[k + 1][colq * 4];
            float4 w2 = *(const float4*)&Wp[k + 2][colq * 4];
            float4 w3 = *(const float4*)&Wp[k + 3][colq * 4];
            float4 x0 = *(const float4*)&xr0[k];
            float4 x1 = *(const float4*)&xr1[k];
            float4 x2 = *(const float4*)&xr2[k];
            float4 x3 = *(const float4*)&xr3[k];
            fma4(acc[0], x0.x, w0); fma4(acc[0], x0.y, w1);
            fma4(acc[0], x0.z, w2); fma4(acc[0], x0.w, w3);
            fma4(acc[1], x1.x, w0); fma4(acc[1], x1.y, w1);
            fma4(acc[1], x1.z, w2); fma4(acc[1], x1.w, w3);
            fma4(acc[2], x2.x, w0); fma4(acc[2], x2.y, w1);
            fma4(acc[2], x2.z, w2); fma4(acc[2], x2.w, w3);
            fma4(acc[3], x3.x, w0); fma4(acc[3], x3.y, w1);
            fma4(acc[3], x3.z, w2); fma4(acc[3], x3.w, w3);
        }
    }
    const int cc = c0 + colq * 4;
    if (cc <= XGS - 4) {                      // cc <= 148; cols 150/151 unread pad
        float4 bv = *(const float4*)&bias[cc];
        #pragma unroll
        for (int j = 0; j < 4; ++j) {
            float4 o;
            o.x = acc[j].x + bv.x; o.y = acc[j].y + bv.y;
            o.z = acc[j].z + bv.z; o.w = acc[j].w + bv.w;
            *(float4*)&xg[(size_t)(m0 + rowq * 4 + j) * XGS + cc] = o;
        }
    }
}

// ---------------- Layer-0 GRU: h in registers, readlane broadcast ----------------
// (unchanged from round 5 -- proven; consumes xg with XGS stride)
template<int WPB, int RPW>
__global__ __launch_bounds__(WPB * 64) void gru_reg(
    const float* __restrict__ xg,             // [dn*Nbatch, XGS] f32 (includes bi)
    const float* __restrict__ U,              // [50,150] f32
    const float* __restrict__ bias,           // [2,150] f32 (br = bias+150)
    float* __restrict__ Xout,                 // [MTOT,50] f32 time-major
    int dn, int Nbatch, int ngroups)
{
    constexpr int R = WPB * RPW;              // rows per block per group
    __shared__ __align__(16) float Ut[HH][HH][4];   // [k][unit][{z,r,h,0}] 40 KB

    const int tid  = threadIdx.x;
    const int wav  = tid >> 6;
    const int lane = tid & 63;

    for (int i = tid; i < HH * HH; i += WPB * 64)
        Ut[i / HH][i - (i / HH) * HH][3] = 0.f;
    for (int i = tid; i < HH * GG; i += WPB * 64) {
        int k = i / GG, cc = i - k * GG;
        Ut[k][cc % HH][cc / HH] = U[i];       // U cols: [z|r|h] blocks of 50
    }
    __syncthreads();                          // the only block-wide barrier

    const int c  = lane;
    const int cb = (c < HH) ? c : HH - 1;     // clamped for loads (lanes 50..63)

    const float bz  = bias[GG + cb];
    const float brr = bias[GG + HH + cb];
    const float bh  = bias[GG + 2 * HH + cb];

    for (int grp = blockIdx.x; grp < ngroups; grp += gridDim.x) {
        const int row0 = grp * R + wav * RPW;
        float h[RPW];
        #pragma unroll
        for (int j = 0; j < RPW; ++j) h[j] = 0.f;
        size_t obase[RPW];
        #pragma unroll
        for (int j = 0; j < RPW; ++j) {
            int nr = row0 + j;
            obase[j] = ((size_t)((nr >> 6) * dn) * NB + (nr & 63)) * HH + cb;
        }
        const float* gb = xg + (size_t)row0 * XGS;

        float px[RPW], pr[RPW], ph[RPW];
        #pragma unroll
        for (int j = 0; j < RPW; ++j) {       // preload step 0
            const float* g = gb + (size_t)j * XGS;
            px[j] = g[cb]; pr[j] = g[HH + cb]; ph[j] = g[2 * HH + cb];
        }

        for (int s = 0; s < dn; ++s) {
            const int sn = (s + 1 < dn) ? s + 1 : s;
            float nx[RPW], nrr[RPW], nh[RPW];
            #pragma unroll
            for (int j = 0; j < RPW; ++j) {
                const float* g = gb + ((size_t)sn * Nbatch + j) * XGS;
                nx[j] = g[cb]; nrr[j] = g[HH + cb]; nh[j] = g[2 * HH + cb];
            }
            float az[RPW], ar[RPW], ah[RPW];
            #pragma unroll
            for (int j = 0; j < RPW; ++j) { az[j] = bz; ar[j] = brr; ah[j] = bh; }
            #pragma unroll
            for (int k = 0; k < HH; ++k) {
                float4 w = *(const float4*)&Ut[k][c < HH ? c : 0][0];
                #pragma unroll
                for (int j = 0; j < RPW; ++j) {
                    float hk = bcast(h[j], k);
                    az[j] += hk * w.x;
                    ar[j] += hk * w.y;
                    ah[j] += hk * w.z;
                }
            }
            #pragma unroll
            for (int j = 0; j < RPW; ++j) {
                float z  = sigm(px[j] + az[j]);
                float r  = sigm(pr[j] + ar[j]);
                float hh = tanh_f(ph[j] + r * ah[j]);
                float hn = z * h[j] + (1.f - z) * hh;
                h[j] = hn;
                if (c < HH) Xout[obase[j] + (size_t)s * NB * HH] = hn;
            }
            #pragma unroll
            for (int j = 0; j < RPW; ++j) { px[j] = nx[j]; pr[j] = nrr[j]; ph[j] = nh[j]; }
        }
    }
}

// ---------------- Fused projection + GRU (layers 1..5), bounded-unroll ----------------
// Same numerics as round 7 (passed correctness). Spill fix: `#pragma unroll 5`
// on both k-loops bounds the scheduler's ds_read hoisting to ~5 in-flight
// b128 loads (full unroll let it hoist all 50 -> 200 live VGPRs -> scratch
// spill, 4.3 GB phantom FETCH, VALUBusy 6.9%). k stays wave-uniform so
// v_readlane takes an SGPR lane index. RPW=2 single instantiation; LDS 80 KB
// -> 2 blocks/CU, 8 waves/CU at WPB=4.
template<int WPB, int RPW>
__global__ __launch_bounds__(WPB * 64) void gru_fused(
    const float* __restrict__ Xin,            // [dn*Nbatch, HH] f32 (prev layer)
    const float* __restrict__ W,              // [50,150] f32
    const float* __restrict__ U,              // [50,150] f32
    const float* __restrict__ bias,           // [2,150] f32
    float* __restrict__ Xout,                 // [MTOT,50] f32 time-major
    int dn, int Nbatch, int ngroups)
{
    constexpr int R = WPB * RPW;              // rows per block per group
    __shared__ __align__(16) float Ut[HH][HH][4];   // 40 KB
    __shared__ __align__(16) float Wt[HH][HH][4];   // 40 KB

    const int tid  = threadIdx.x;
    const int wav  = tid >> 6;
    const int lane = tid & 63;

    for (int i = tid; i < HH * HH; i += WPB * 64) {
        Ut[i / HH][i - (i / HH) * HH][3] = 0.f;
        Wt[i / HH][i - (i / HH) * HH][3] = 0.f;
    }
    for (int i = tid; i < HH * GG; i += WPB * 64) {
        int k = i / GG, cc = i - k * GG;
        Ut[k][cc % HH][cc / HH] = U[i];
        Wt[k][cc % HH][cc / HH] = W[i];
    }
    __syncthreads();                          // the only block-wide barrier

    const int c  = lane;
    const int cb = (c < HH) ? c : HH - 1;

    const float biz = bias[cb];
    const float bir = bias[HH + cb];
    const float bih = bias[2 * HH + cb];
    const float brz = bias[GG + cb];
    const float brr = bias[GG + HH + cb];
    const float brh = bias[GG + 2 * HH + cb];

    for (int grp = blockIdx.x; grp < ngroups; grp += gridDim.x) {
        const int row0 = grp * R + wav * RPW;
        float h[RPW];
        #pragma unroll
        for (int j = 0; j < RPW; ++j) h[j] = 0.f;
        size_t obase[RPW];
        #pragma unroll
        for (int j = 0; j < RPW; ++j) {
            int nr = row0 + j;
            obase[j] = ((size_t)((nr >> 6) * dn) * NB + (nr & 63)) * HH + cb;
        }
        const float* gb = Xin + (size_t)row0 * HH;

        float px[RPW];
        #pragma unroll
        for (int j = 0; j < RPW; ++j) px[j] = gb[(size_t)j * HH + cb];   // step 0

        for (int s = 0; s < dn; ++s) {
            const int sn = (s + 1 < dn) ? s + 1 : s;
            float nx[RPW];
            #pragma unroll
            for (int j = 0; j < RPW; ++j)
                nx[j] = gb[((size_t)sn * Nbatch + j) * HH + cb];

            // ---- loop 1: x-projection  gz/gr/gh = x @ W + bi ----
            float gz[RPW], gr[RPW], gh[RPW];
            #pragma unroll
            for (int j = 0; j < RPW; ++j) { gz[j] = biz; gr[j] = bir; gh[j] = bih; }
            #pragma unroll 5
            for (int k = 0; k < HH; ++k) {
                float4 w = *(const float4*)&Wt[k][c < HH ? c : 0][0];
                #pragma unroll
                for (int j = 0; j < RPW; ++j) {
                    float xk = bcast(px[j], k);
                    gz[j] += xk * w.x;
                    gr[j] += xk * w.y;
                    gh[j] += xk * w.z;
                }
            }
            // ---- loop 2: recurrence  az/ar/ah = h @ U + br ----
            float az[RPW], ar[RPW], ah[RPW];
            #pragma unroll
            for (int j = 0; j < RPW; ++j) { az[j] = brz; ar[j] = brr; ah[j] = brh; }
            #pragma unroll 5
            for (int k = 0; k < HH; ++k) {
                float4 w = *(const float4*)&Ut[k][c < HH ? c : 0][0];
                #pragma unroll
                for (int j = 0; j < RPW; ++j) {
                    float hk = bcast(h[j], k);
                    az[j] += hk * w.x;
                    ar[j] += hk * w.y;
                    ah[j] += hk * w.z;
                }
            }
            // ---- gates + state update ----
            #pragma unroll
            for (int j = 0; j < RPW; ++j) {
                float z  = sigm(gz[j] + az[j]);
                float r  = sigm(gr[j] + ar[j]);
                float hh = tanh_f(gh[j] + r * ah[j]);
                float hn = z * h[j] + (1.f - z) * hh;
                h[j] = hn;
                if (c < HH) Xout[obase[j] + (size_t)s * NB * HH] = hn;
            }
            #pragma unroll
            for (int j = 0; j < RPW; ++j) px[j] = nx[j];
        }
    }
}

// ---------------- Head: split-K partial GEMM (no bias/relu here) ----------------
__global__ __launch_bounds__(256) void dense2_kernel(
    const float* __restrict__ X,              // [MTOT,50] f32 final layer (time-major)
    const float* __restrict__ W2,             // [1600,1600] f32
    float* __restrict__ part)                 // [16,64,1600] f32 partials
{
    __shared__ float fs[8][100];              // 3.2 KB
    const int tid = threadIdx.x;
    const int c  = blockIdx.x * 256 + tid;
    const int r0 = blockIdx.y * 8;
    const int kz = blockIdx.z;
    for (int i = tid; i < 8 * 100; i += 256) {
        int r = i / 100, fl = i - r * 100;
        int f = kz * 100 + fl, j = f / HH, k = f - j * HH;
        fs[r][fl] = X[((size_t)(TTT - 32 + j) * NB + (r0 + r)) * HH + k];
    }
    __syncthreads();
    if (c < 1600) {
        float a[8] = {0, 0, 0, 0, 0, 0, 0, 0};
        const float* w = W2 + (size_t)kz * 100 * 1600 + c;
        for (int fl = 0; fl < 100; ++fl) {
            float wv = w[(size_t)fl * 1600];
            #pragma unroll
            for (int r = 0; r < 8; ++r) a[r] += fs[r][fl] * wv;
        }
        #pragma unroll
        for (int r = 0; r < 8; ++r)
            part[((size_t)kz * NB + r0 + r) * 1600 + c] = a[r];
    }
}

// ---------------- Classifier: sum partials + bias + relu, then softmax ----------------
__global__ __launch_bounds__(256) void cls_kernel(
    const float* __restrict__ part,           // [16,64,1600] f32 partials
    const float* __restrict__ b2,             // [1600] f32
    const float* __restrict__ Wc,             // [1600,41] f32
    const float* __restrict__ bc,             // [41] f32
    float* __restrict__ out)                  // [64,41] f32
{
    __shared__ float hrow[1600];
    __shared__ float lg[41];
    __shared__ float red[2];
    const int b = blockIdx.x;
    const int t = threadIdx.x;
    for (int i = t; i < 1600; i += 256) {
        float s = b2[i];
        #pragma unroll 4
        for (int kz = 0; kz < 16; ++kz)
            s += part[((size_t)kz * NB + b) * 1600 + i];
        hrow[i] = s > 0.f ? s : 0.f;
    }
    __syncthreads();
    if (t < 41) {
        float acc = bc[t];
        for (int f = 0; f < 1600; ++f) acc += hrow[f] * Wc[f * 41 + t];
        lg[t] = acc;
    }
    __syncthreads();
    if (t == 0) {
        float mx = lg[0];
        for (int i = 1; i < 41; ++i) mx = fmaxf(mx, lg[i]);
        red[0] = mx;
    }
    __syncthreads();
    if (t < 41) lg[t] = expf(lg[t] - red[0]);
    __syncthreads();
    if (t == 0) {
        float sm = 0.f;
        for (int i = 0; i < 41; ++i) sm += lg[i];
        red[1] = 1.f / sm;
    }
    __syncthreads();
    if (t < 41) out[b * 41 + t] = lg[t] * red[1];
}

extern "C" void kernel_launch(void* const* d_in, const int* in_sizes, int n_in,
                              void* d_out, int out_size, void* d_ws, size_t ws_size,
                              hipStream_t stream)
{
    const float* x   = (const float*)d_in[0];    // [64,2048,128]
    const float* W0  = (const float*)d_in[1];    // [128,150]
    const float* U0  = (const float*)d_in[2];    // [50,150]
    const float* b0  = (const float*)d_in[3];    // [2,150]
    const float* Ws  = (const float*)d_in[4];    // [5,50,150]
    const float* Us  = (const float*)d_in[5];    // [5,50,150]
    const float* bs  = (const float*)d_in[6];    // [5,2,150]
    const float* W2  = (const float*)d_in[7];    // [1600,1600]
    const float* b2  = (const float*)d_in[8];    // [1600]
    const float* Wc  = (const float*)d_in[9];    // [1600,41]
    const float* bc  = (const float*)d_in[10];   // [41]

    // Workspace layout:
    //   region1 = MTOT*XGS floats (79.7 MB): xg (layer 0) -> bufB (layers 1..5)
    //             part lives at region1 + MTOT*HH (disjoint from bufB)
    //   bufA    = MTOT*HH floats (26.2 MB)
    float* region1 = (float*)d_ws;
    float* xg   = region1;
    float* bufB = region1;                             // reuses xg after layer 0
    float* part = region1 + (size_t)MTOT * HH;         // disjoint from bufB
    float* bufA = region1 + (size_t)MTOT * XGS;

    static const int rates[6] = {32, 64, 128, 256, 512, 1024};

    // ---- layer 0: GEMM proj + gru_reg (round-5 proven config) ----
    proj0_kernel<<<dim3(MTOT / 128, 5), 256, 0, stream>>>(x, W0, b0, xg);
    {
        int dn = TTT / rates[0], Nbatch = rates[0] * NB;   // 64, 2048
        int ngroups = Nbatch / 4;                          // R=4 for <4,1>
        int grid = ngroups < 1024 ? ngroups : 1024;
        gru_reg<4, 1><<<grid, 256, 0, stream>>>(xg, U0, b0, bufA, dn, Nbatch, ngroups);
    }

    // ---- layers 1..5: fused proj+gru <4,2>, ping-pong bufA <-> bufB ----
    const float* cur = bufA;
    for (int l = 1; l < 6; ++l) {
        const float* Wl = Ws + (size_t)(l - 1) * HH * GG;
        const float* Ul = Us + (size_t)(l - 1) * HH * GG;
        const float* bl = bs + (size_t)(l - 1) * 2 * GG;
        int rate = rates[l];
        int Nbatch = rate * NB;
        int dn = TTT / rate;
        float* dst = (cur == bufA) ? bufB : bufA;
        int ngroups = Nbatch / 8;                          // R=8 for <4,2>
        int grid = ngroups < 512 ? ngroups : 512;
        gru_fused<4, 2><<<grid, 256, 0, stream>>>(cur, Wl, Ul, bl, dst, dn, Nbatch, ngroups);
        cur = dst;
    }

    // head: split-K dense2 into partials, reduce+relu inside cls
    dense2_kernel<<<dim3(7, 8, 16), 256, 0, stream>>>(cur, W2, part);
    cls_kernel<<<NB, 256, 0, stream>>>(part, b2, Wc, bc, (float*)d_out);
}

// Round 9
// 1031.327 us; speedup vs baseline: 16.2150x; 1.0959x over previous
//
#include <hip/hip_runtime.h>
#include <math.h>

// Dims (fixed by the problem)
#define HH   50          // hidden
#define GG   150         // 3H
#define XGS  152         // xg row stride (padded)
#define TTT  2048        // T
#define NB   64          // batch B
#define MTOT (TTT*NB)    // 131072 rows per layer
#define D0   128         // layer-0 input dim

static __device__ __forceinline__ float sigm(float x) {
    return 1.f / (1.f + __expf(-x));
}
static __device__ __forceinline__ float tanh_f(float x) {
    return 1.f - 2.f / (__expf(2.f * x) + 1.f);   // saturates correctly at +/-inf
}

static __device__ __forceinline__ void fma4(float4& a, float s, const float4& w) {
    a.x += s * w.x; a.y += s * w.y; a.z += s * w.z; a.w += s * w.w;
}

static __device__ __forceinline__ float bcast(float v, int k) {
    // wave-uniform broadcast of lane k's value (v_readlane_b32, SGPR lane idx)
    return __uint_as_float(__builtin_amdgcn_readlane(__float_as_uint(v), k));
}

// ---------------- Layer-0 input projection: Xg = X0 @ W + bi ----------------
// (unchanged -- proven, ~110 us)
__global__ __launch_bounds__(256) void proj0_kernel(
    const float* __restrict__ x,              // [64,2048,128] f32
    const float* __restrict__ W,              // [128,150] f32
    const float* __restrict__ bias,           // [2,150] f32 (bi = bias[0])
    float* __restrict__ xg)                   // [MTOT,XGS] f32
{
    __shared__ float xs[128][36];             // k-quarter of x, stride 36 (18.4 KB)
    __shared__ float Wp[32][32];              // k-quarter of W cols for this tile (4 KB)
    const int tid  = threadIdx.x;
    const int m0   = blockIdx.x * 128;
    const int c0   = blockIdx.y * 32;         // col-tile base: 0,32,64,96,128
    const int rowq = tid >> 3;                // 0..31
    const int colq = tid & 7;                 // 0..7

    float4 acc[4];
    #pragma unroll
    for (int j = 0; j < 4; ++j) acc[j] = make_float4(0.f, 0.f, 0.f, 0.f);

    for (int q = 0; q < 4; ++q) {             // K quarters of 32
        if (q) __syncthreads();
        for (int i = tid; i < 128 * 8; i += 256) {
            int r = i >> 3, k4 = (i & 7) * 4;
            int row = m0 + r, t = row >> 6, b = row & 63;
            *(float4*)&xs[r][k4] =
                *(const float4*)&x[((size_t)b * TTT + t) * D0 + q * 32 + k4];
        }
        for (int i = tid; i < 32 * 32; i += 256) {
            int k = i >> 5, c = i & 31, gc = c0 + c;
            Wp[k][c] = (gc < GG) ? W[(q * 32 + k) * GG + gc] : 0.f;
        }
        __syncthreads();
        const float* xr0 = xs[rowq * 4 + 0];
        const float* xr1 = xs[rowq * 4 + 1];
        const float* xr2 = xs[rowq * 4 + 2];
        const float* xr3 = xs[rowq * 4 + 3];
        for (int k = 0; k < 32; k += 4) {
            float4 w0 = *(const float4*)&Wp[k + 0][colq * 4];
            float4 w1 = *(const float4*)&Wp[k + 1][colq * 4];
            float4 w2 = *(const float4*)&Wp[k + 2][colq * 4];
            float4 w3 = *(const float4*)&Wp[k + 3][colq * 4];
            float4 x0 = *(const float4*)&xr0[k];
            float4 x1 = *(const float4*)&xr1[k];
            float4 x2 = *(const float4*)&xr2[k];
            float4 x3 = *(const float4*)&xr3[k];
            fma4(acc[0], x0.x, w0); fma4(acc[0], x0.y, w1);
            fma4(acc[0], x0.z, w2); fma4(acc[0], x0.w, w3);
            fma4(acc[1], x1.x, w0); fma4(acc[1], x1.y, w1);
            fma4(acc[1], x1.z, w2); fma4(acc[1], x1.w, w3);
            fma4(acc[2], x2.x, w0); fma4(acc[2], x2.y, w1);
            fma4(acc[2], x2.z, w2); fma4(acc[2], x2.w, w3);
            fma4(acc[3], x3.x, w0); fma4(acc[3], x3.y, w1);
            fma4(acc[3], x3.z, w2); fma4(acc[3], x3.w, w3);
        }
    }
    const int cc = c0 + colq * 4;
    if (cc <= XGS - 4) {                      // cc <= 148; cols 150/151 unread pad
        float4 bv = *(const float4*)&bias[cc];
        #pragma unroll
        for (int j = 0; j < 4; ++j) {
            float4 o;
            o.x = acc[j].x + bv.x; o.y = acc[j].y + bv.y;
            o.z = acc[j].z + bv.z; o.w = acc[j].w + bv.w;
            *(float4*)&xg[(size_t)(m0 + rowq * 4 + j) * XGS + cc] = o;
        }
    }
}

// ---------------- Layer-0 GRU: h in registers, readlane broadcast ----------------
// Round-5 proven structure; k-loop now `#pragma unroll 5` (spill-guard at
// RPW=2: full unroll lets the scheduler hoist all 50 ds_read_b128 -> 200 live
// VGPRs -> scratch spill, seen rounds 6/7). LDS weight stream per row-step
// halves at RPW=2 vs RPW=1 (the round-8 finding: this kernel class is
// LDS-bandwidth-bound on weight streaming; traffic ~ 1/RPW).
template<int WPB, int RPW>
__global__ __launch_bounds__(WPB * 64) void gru_reg(
    const float* __restrict__ xg,             // [dn*Nbatch, XGS] f32 (includes bi)
    const float* __restrict__ U,              // [50,150] f32
    const float* __restrict__ bias,           // [2,150] f32 (br = bias+150)
    float* __restrict__ Xout,                 // [MTOT,50] f32 time-major
    int dn, int Nbatch, int ngroups)
{
    constexpr int R = WPB * RPW;              // rows per block per group
    __shared__ __align__(16) float Ut[HH][HH][4];   // [k][unit][{z,r,h,0}] 40 KB

    const int tid  = threadIdx.x;
    const int wav  = tid >> 6;
    const int lane = tid & 63;

    for (int i = tid; i < HH * HH; i += WPB * 64)
        Ut[i / HH][i - (i / HH) * HH][3] = 0.f;
    for (int i = tid; i < HH * GG; i += WPB * 64) {
        int k = i / GG, cc = i - k * GG;
        Ut[k][cc % HH][cc / HH] = U[i];       // U cols: [z|r|h] blocks of 50
    }
    __syncthreads();                          // the only block-wide barrier

    const int c  = lane;
    const int cb = (c < HH) ? c : HH - 1;     // clamped for loads (lanes 50..63)

    const float bz  = bias[GG + cb];
    const float brr = bias[GG + HH + cb];
    const float bh  = bias[GG + 2 * HH + cb];

    for (int grp = blockIdx.x; grp < ngroups; grp += gridDim.x) {
        const int row0 = grp * R + wav * RPW;
        float h[RPW];
        #pragma unroll
        for (int j = 0; j < RPW; ++j) h[j] = 0.f;
        size_t obase[RPW];
        #pragma unroll
        for (int j = 0; j < RPW; ++j) {
            int nr = row0 + j;
            obase[j] = ((size_t)((nr >> 6) * dn) * NB + (nr & 63)) * HH + cb;
        }
        const float* gb = xg + (size_t)row0 * XGS;

        float px[RPW], pr[RPW], ph[RPW];
        #pragma unroll
        for (int j = 0; j < RPW; ++j) {       // preload step 0
            const float* g = gb + (size_t)j * XGS;
            px[j] = g[cb]; pr[j] = g[HH + cb]; ph[j] = g[2 * HH + cb];
        }

        for (int s = 0; s < dn; ++s) {
            const int sn = (s + 1 < dn) ? s + 1 : s;
            float nx[RPW], nrr[RPW], nh[RPW];
            #pragma unroll
            for (int j = 0; j < RPW; ++j) {
                const float* g = gb + ((size_t)sn * Nbatch + j) * XGS;
                nx[j] = g[cb]; nrr[j] = g[HH + cb]; nh[j] = g[2 * HH + cb];
            }
            float az[RPW], ar[RPW], ah[RPW];
            #pragma unroll
            for (int j = 0; j < RPW; ++j) { az[j] = bz; ar[j] = brr; ah[j] = bh; }
            #pragma unroll 5
            for (int k = 0; k < HH; ++k) {
                float4 w = *(const float4*)&Ut[k][c < HH ? c : 0][0];
                #pragma unroll
                for (int j = 0; j < RPW; ++j) {
                    float hk = bcast(h[j], k);
                    az[j] += hk * w.x;
                    ar[j] += hk * w.y;
                    ah[j] += hk * w.z;
                }
            }
            #pragma unroll
            for (int j = 0; j < RPW; ++j) {
                float z  = sigm(px[j] + az[j]);
                float r  = sigm(pr[j] + ar[j]);
                float hh = tanh_f(ph[j] + r * ah[j]);
                float hn = z * h[j] + (1.f - z) * hh;
                h[j] = hn;
                if (c < HH) Xout[obase[j] + (size_t)s * NB * HH] = hn;
            }
            #pragma unroll
            for (int j = 0; j < RPW; ++j) { px[j] = nx[j]; pr[j] = nrr[j]; ph[j] = nh[j]; }
        }
    }
}

// ---------------- Fused projection + GRU (layers 1..5), bounded-unroll ----------------
// Round-8 proven (VGPR 88, no spill). LDS-BW-bound on weight streaming:
// 100 ds_read_b128 per wave-step amortized over RPW rows -> traffic ~ 1/RPW.
// This round: RPW raised to the occupancy limit per layer (4 or 8).
template<int WPB, int RPW>
__global__ __launch_bounds__(WPB * 64) void gru_fused(
    const float* __restrict__ Xin,            // [dn*Nbatch, HH] f32 (prev layer)
    const float* __restrict__ W,              // [50,150] f32
    const float* __restrict__ U,              // [50,150] f32
    const float* __restrict__ bias,           // [2,150] f32
    float* __restrict__ Xout,                 // [MTOT,50] f32 time-major
    int dn, int Nbatch, int ngroups)
{
    constexpr int R = WPB * RPW;              // rows per block per group
    __shared__ __align__(16) float Ut[HH][HH][4];   // 40 KB
    __shared__ __align__(16) float Wt[HH][HH][4];   // 40 KB

    const int tid  = threadIdx.x;
    const int wav  = tid >> 6;
    const int lane = tid & 63;

    for (int i = tid; i < HH * HH; i += WPB * 64) {
        Ut[i / HH][i - (i / HH) * HH][3] = 0.f;
        Wt[i / HH][i - (i / HH) * HH][3] = 0.f;
    }
    for (int i = tid; i < HH * GG; i += WPB * 64) {
        int k = i / GG, cc = i - k * GG;
        Ut[k][cc % HH][cc / HH] = U[i];
        Wt[k][cc % HH][cc / HH] = W[i];
    }
    __syncthreads();                          // the only block-wide barrier

    const int c  = lane;
    const int cb = (c < HH) ? c : HH - 1;

    const float biz = bias[cb];
    const float bir = bias[HH + cb];
    const float bih = bias[2 * HH + cb];
    const float brz = bias[GG + cb];
    const float brr = bias[GG + HH + cb];
    const float brh = bias[GG + 2 * HH + cb];

    for (int grp = blockIdx.x; grp < ngroups; grp += gridDim.x) {
        const int row0 = grp * R + wav * RPW;
        float h[RPW];
        #pragma unroll
        for (int j = 0; j < RPW; ++j) h[j] = 0.f;
        size_t obase[RPW];
        #pragma unroll
        for (int j = 0; j < RPW; ++j) {
            int nr = row0 + j;
            obase[j] = ((size_t)((nr >> 6) * dn) * NB + (nr & 63)) * HH + cb;
        }
        const float* gb = Xin + (size_t)row0 * HH;

        float px[RPW];
        #pragma unroll
        for (int j = 0; j < RPW; ++j) px[j] = gb[(size_t)j * HH + cb];   // step 0

        for (int s = 0; s < dn; ++s) {
            const int sn = (s + 1 < dn) ? s + 1 : s;
            float nx[RPW];
            #pragma unroll
            for (int j = 0; j < RPW; ++j)
                nx[j] = gb[((size_t)sn * Nbatch + j) * HH + cb];

            // ---- loop 1: x-projection  gz/gr/gh = x @ W + bi ----
            float gz[RPW], gr[RPW], gh[RPW];
            #pragma unroll
            for (int j = 0; j < RPW; ++j) { gz[j] = biz; gr[j] = bir; gh[j] = bih; }
            #pragma unroll 5
            for (int k = 0; k < HH; ++k) {
                float4 w = *(const float4*)&Wt[k][c < HH ? c : 0][0];
                #pragma unroll
                for (int j = 0; j < RPW; ++j) {
                    float xk = bcast(px[j], k);
                    gz[j] += xk * w.x;
                    gr[j] += xk * w.y;
                    gh[j] += xk * w.z;
                }
            }
            // ---- loop 2: recurrence  az/ar/ah = h @ U + br ----
            float az[RPW], ar[RPW], ah[RPW];
            #pragma unroll
            for (int j = 0; j < RPW; ++j) { az[j] = brz; ar[j] = brr; ah[j] = brh; }
            #pragma unroll 5
            for (int k = 0; k < HH; ++k) {
                float4 w = *(const float4*)&Ut[k][c < HH ? c : 0][0];
                #pragma unroll
                for (int j = 0; j < RPW; ++j) {
                    float hk = bcast(h[j], k);
                    az[j] += hk * w.x;
                    ar[j] += hk * w.y;
                    ah[j] += hk * w.z;
                }
            }
            // ---- gates + state update ----
            #pragma unroll
            for (int j = 0; j < RPW; ++j) {
                float z  = sigm(gz[j] + az[j]);
                float r  = sigm(gr[j] + ar[j]);
                float hh = tanh_f(gh[j] + r * ah[j]);
                float hn = z * h[j] + (1.f - z) * hh;
                h[j] = hn;
                if (c < HH) Xout[obase[j] + (size_t)s * NB * HH] = hn;
            }
            #pragma unroll
            for (int j = 0; j < RPW; ++j) px[j] = nx[j];
        }
    }
}

// ---------------- Head: split-K partial GEMM (no bias/relu here) ----------------
__global__ __launch_bounds__(256) void dense2_kernel(
    const float* __restrict__ X,              // [MTOT,50] f32 final layer (time-major)
    const float* __restrict__ W2,             // [1600,1600] f32
    float* __restrict__ part)                 // [16,64,1600] f32 partials
{
    __shared__ float fs[8][100];              // 3.2 KB
    const int tid = threadIdx.x;
    const int c  = blockIdx.x * 256 + tid;
    const int r0 = blockIdx.y * 8;
    const int kz = blockIdx.z;
    for (int i = tid; i < 8 * 100; i += 256) {
        int r = i / 100, fl = i - r * 100;
        int f = kz * 100 + fl, j = f / HH, k = f - j * HH;
        fs[r][fl] = X[((size_t)(TTT - 32 + j) * NB + (r0 + r)) * HH + k];
    }
    __syncthreads();
    if (c < 1600) {
        float a[8] = {0, 0, 0, 0, 0, 0, 0, 0};
        const float* w = W2 + (size_t)kz * 100 * 1600 + c;
        for (int fl = 0; fl < 100; ++fl) {
            float wv = w[(size_t)fl * 1600];
            #pragma unroll
            for (int r = 0; r < 8; ++r) a[r] += fs[r][fl] * wv;
        }
        #pragma unroll
        for (int r = 0; r < 8; ++r)
            part[((size_t)kz * NB + r0 + r) * 1600 + c] = a[r];
    }
}

// ---------------- Classifier: sum partials + bias + relu, then softmax ----------------
__global__ __launch_bounds__(256) void cls_kernel(
    const float* __restrict__ part,           // [16,64,1600] f32 partials
    const float* __restrict__ b2,             // [1600] f32
    const float* __restrict__ Wc,             // [1600,41] f32
    const float* __restrict__ bc,             // [41] f32
    float* __restrict__ out)                  // [64,41] f32
{
    __shared__ float hrow[1600];
    __shared__ float lg[41];
    __shared__ float red[2];
    const int b = blockIdx.x;
    const int t = threadIdx.x;
    for (int i = t; i < 1600; i += 256) {
        float s = b2[i];
        #pragma unroll 4
        for (int kz = 0; kz < 16; ++kz)
            s += part[((size_t)kz * NB + b) * 1600 + i];
        hrow[i] = s > 0.f ? s : 0.f;
    }
    __syncthreads();
    if (t < 41) {
        float acc = bc[t];
        for (int f = 0; f < 1600; ++f) acc += hrow[f] * Wc[f * 41 + t];
        lg[t] = acc;
    }
    __syncthreads();
    if (t == 0) {
        float mx = lg[0];
        for (int i = 1; i < 41; ++i) mx = fmaxf(mx, lg[i]);
        red[0] = mx;
    }
    __syncthreads();
    if (t < 41) lg[t] = expf(lg[t] - red[0]);
    __syncthreads();
    if (t == 0) {
        float sm = 0.f;
        for (int i = 0; i < 41; ++i) sm += lg[i];
        red[1] = 1.f / sm;
    }
    __syncthreads();
    if (t < 41) out[b * 41 + t] = lg[t] * red[1];
}

extern "C" void kernel_launch(void* const* d_in, const int* in_sizes, int n_in,
                              void* d_out, int out_size, void* d_ws, size_t ws_size,
                              hipStream_t stream)
{
    const float* x   = (const float*)d_in[0];    // [64,2048,128]
    const float* W0  = (const float*)d_in[1];    // [128,150]
    const float* U0  = (const float*)d_in[2];    // [50,150]
    const float* b0  = (const float*)d_in[3];    // [2,150]
    const float* Ws  = (const float*)d_in[4];    // [5,50,150]
    const float* Us  = (const float*)d_in[5];    // [5,50,150]
    const float* bs  = (const float*)d_in[6];    // [5,2,150]
    const float* W2  = (const float*)d_in[7];    // [1600,1600]
    const float* b2  = (const float*)d_in[8];    // [1600]
    const float* Wc  = (const float*)d_in[9];    // [1600,41]
    const float* bc  = (const float*)d_in[10];   // [41]

    // Workspace layout:
    //   region1 = MTOT*XGS floats (79.7 MB): xg (layer 0) -> bufB (layers 1..5)
    //             part lives at region1 + MTOT*HH (disjoint from bufB)
    //   bufA    = MTOT*HH floats (26.2 MB)
    float* region1 = (float*)d_ws;
    float* xg   = region1;
    float* bufB = region1;                             // reuses xg after layer 0
    float* part = region1 + (size_t)MTOT * HH;         // disjoint from bufB
    float* bufA = region1 + (size_t)MTOT * XGS;

    static const int rates[6] = {32, 64, 128, 256, 512, 1024};

    // ---- layer 0: GEMM proj + gru_reg (RPW=2: halves LDS weight stream) ----
    proj0_kernel<<<dim3(MTOT / 128, 5), 256, 0, stream>>>(x, W0, b0, xg);
    {
        int dn = TTT / rates[0], Nbatch = rates[0] * NB;   // 64, 2048
        int ngroups = Nbatch / 8;                          // R=8 for <4,2>
        int grid = ngroups < 512 ? ngroups : 512;
        gru_reg<4, 2><<<grid, 256, 0, stream>>>(xg, U0, b0, bufA, dn, Nbatch, ngroups);
    }

    // ---- layers 1..5: fused proj+gru, RPW at the occupancy limit ----
    const float* cur = bufA;
    for (int l = 1; l < 6; ++l) {
        const float* Wl = Ws + (size_t)(l - 1) * HH * GG;
        const float* Ul = Us + (size_t)(l - 1) * HH * GG;
        const float* bl = bs + (size_t)(l - 1) * 2 * GG;
        int rate = rates[l];
        int Nbatch = rate * NB;
        int dn = TTT / rate;
        float* dst = (cur == bufA) ? bufB : bufA;
        if (l <= 2) {                                      // RPW=4: R=16
            int ngroups = Nbatch / 16;
            int grid = ngroups < 512 ? ngroups : 512;
            gru_fused<4, 4><<<grid, 256, 0, stream>>>(cur, Wl, Ul, bl, dst, dn, Nbatch, ngroups);
        } else {                                           // RPW=8: R=32
            int ngroups = Nbatch / 32;
            int grid = ngroups < 512 ? ngroups : 512;
            gru_fused<4, 8><<<grid, 256, 0, stream>>>(cur, Wl, Ul, bl, dst, dn, Nbatch, ngroups);
        }
        cur = dst;
    }
    // ping-pong: A->B->A->B->A->B; final cur = bufB (disjoint from part)

    // head: split-K dense2 into partials, reduce+relu inside cls
    dense2_kernel<<<dim3(7, 8, 16), 256, 0, stream>>>(cur, W2, part);
    cls_kernel<<<NB, 256, 0, stream>>>(part, b2, Wc, bc, (float*)d_out);
}